// Round 1
// baseline (443.543 us; speedup 1.0000x reference)
//
#include <hip/hip_runtime.h>
#include <math.h>

#define NB 32
#define NS 4096
#define ND 512
#define NU 128
#define RR 32          // rows of values per block
#define ASTR 520       // A LDS row stride (bf16 elems): 512 + 8 pad (16B-aligned rows, 2-way max conflict)
#define BSTR 40        // B LDS row stride: 32 + 8 pad

typedef __bf16 bf16x8 __attribute__((ext_vector_type(8)));
typedef unsigned short u16x8 __attribute__((ext_vector_type(8)));
typedef float f32x4 __attribute__((ext_vector_type(4)));

union FragCvt { u16x8 u; bf16x8 b; };

__device__ inline unsigned short f2bf(float x) {
  union { float f; unsigned u; } v; v.f = x;
  return (unsigned short)((v.u + 0x7FFFu + ((v.u >> 16) & 1u)) >> 16);
}
__device__ inline float bf2f(unsigned int bits16) {  // low 16 bits are bf16
  union { unsigned u; float f; } v; v.u = bits16 << 16;
  return v.f;
}

// ---------------- prep: qb[b][u] = query@W1 + b1 + b2 ----------------
__global__ void prep_qb(const float* __restrict__ q, const float* __restrict__ W1,
                        const float* __restrict__ b1, const float* __restrict__ b2,
                        float* __restrict__ qb) {
  int idx = blockIdx.x * 256 + threadIdx.x;   // 4096 = 32*128
  int b = idx >> 7, u = idx & 127;
  float s = b1[u] + b2[u];
  const float* qr = q + b * ND;
  for (int d = 0; d < ND; ++d) s += qr[d] * W1[d * NU + u];
  qb[idx] = s;
}

// ---------------- prep: w2t[u][d] = bf16(W2[d][u]) ----------------
__global__ void prep_w2t(const float* __restrict__ W2, unsigned short* __restrict__ w2t) {
  int idx = blockIdx.x * 256 + threadIdx.x;   // 65536 = 128*512
  int u = idx >> 9, d = idx & 511;
  w2t[idx] = f2bf(W2[d * NU + u]);
}

// ---------------- fused: proj -> tanh -> score -> exp -> partial softmax + context ----------------
__global__ __launch_bounds__(256, 3) void fused_attn(
    const float* __restrict__ values,
    const float* __restrict__ qb,            // [NB][NU]
    const unsigned short* __restrict__ w2t,  // [NU][ND] bf16 bits
    const float* __restrict__ V,             // [NU]
    const float* __restrict__ bvp,           // [1]
    float* __restrict__ wout,                // [NB][NS] unnormalized e^s (d_out weights region)
    float* __restrict__ Cacc,                // [NB][ND] partial context (ws, zeroed)
    float* __restrict__ Lacc)                // [NB] partial denom (ws, zeroed)
{
  __shared__ unsigned short Alds[RR * ASTR];     // 33,280 B
  __shared__ unsigned short Blds[NU * BSTR];     // 10,240 B
  __shared__ float sbuf[4][16];
  __shared__ float wlds[RR];

  const int tid = threadIdx.x;
  const int b = blockIdx.x >> 7;        // 128 chunks per batch
  const int chunk = blockIdx.x & 127;
  const int s0 = chunk * RR;

  // ---- stage A: values[b][s0..s0+31][:] fp32 -> bf16 LDS (row-major, padded) ----
  const float* vbase = values + ((size_t)b * NS + s0) * ND;
  #pragma unroll
  for (int i = 0; i < 16; ++i) {
    int f = tid + 256 * i;              // float4 index in [0, 4096)
    int row = f >> 7;                   // 128 float4 per row
    int c4 = f & 127;
    float4 v = *(const float4*)(vbase + row * ND + c4 * 4);
    ushort4 pk;
    pk.x = f2bf(v.x); pk.y = f2bf(v.y); pk.z = f2bf(v.z); pk.w = f2bf(v.w);
    *(ushort4*)(&Alds[row * ASTR + c4 * 4]) = pk;
  }

  const int wave = tid >> 6, lane = tid & 63;
  const int quad = lane >> 4, lidx = lane & 15;
  const int mtile = wave & 1;           // rows mtile*16 .. +15
  const int nbase = (wave >> 1) * 64;   // 4 n-tiles of 16

  f32x4 acc[4] = {{0.f,0.f,0.f,0.f},{0.f,0.f,0.f,0.f},{0.f,0.f,0.f,0.f},{0.f,0.f,0.f,0.f}};

  const int bu = tid >> 1, bh = tid & 1;  // B staging: row u, 16-elem half
  for (int kt = 0; kt < 16; ++kt) {
    __syncthreads();
    // stage B tile: w2t[u][kt*32 .. +32)
    {
      const unsigned short* src = w2t + bu * ND + kt * 32 + bh * 16;
      u16x8 p0 = *(const u16x8*)(src);
      u16x8 p1 = *(const u16x8*)(src + 8);
      *(u16x8*)(&Blds[bu * BSTR + bh * 16])     = p0;
      *(u16x8*)(&Blds[bu * BSTR + bh * 16 + 8]) = p1;
    }
    __syncthreads();
    FragCvt af; af.u = *(const u16x8*)(&Alds[(mtile * 16 + lidx) * ASTR + kt * 32 + quad * 8]);
    #pragma unroll
    for (int nt = 0; nt < 4; ++nt) {
      FragCvt bf; bf.u = *(const u16x8*)(&Blds[(nbase + nt * 16 + lidx) * BSTR + quad * 8]);
      acc[nt] = __builtin_amdgcn_mfma_f32_16x16x32_bf16(af.b, bf.b, acc[nt], 0, 0, 0);
    }
  }

  // ---- epilogue: tanh + dot with V; lane covers rows quad*4+reg (m), cols nbase+nt*16+lidx ----
  float part[4] = {0.f, 0.f, 0.f, 0.f};
  #pragma unroll
  for (int nt = 0; nt < 4; ++nt) {
    int col = nbase + nt * 16 + lidx;
    float qv = qb[b * NU + col];
    float vv = V[col];
    #pragma unroll
    for (int r = 0; r < 4; ++r) {
      float t = tanhf(acc[nt][r] + qv);
      part[r] += t * vv;
    }
  }
  // reduce across the 16 lanes of each quad (sum over n)
  #pragma unroll
  for (int m = 1; m <= 8; m <<= 1) {
    #pragma unroll
    for (int r = 0; r < 4; ++r) part[r] += __shfl_xor(part[r], m, 64);
  }
  if (lidx == 0) {
    #pragma unroll
    for (int r = 0; r < 4; ++r) sbuf[wave][quad * 4 + r] = part[r];
  }
  __syncthreads();

  if (tid < 32) {
    int mt = tid >> 4, rr = tid & 15;
    float s = sbuf[mt][rr] + sbuf[mt + 2][rr];   // waves (0,2) cover mtile0; (1,3) mtile1
    float e = expf(s + *bvp);                    // no max needed: |s| bounded by tanh*||V||
    wout[(size_t)b * NS + s0 + tid] = e;
    wlds[tid] = e;
    float es = e;
    #pragma unroll
    for (int m = 1; m <= 16; m <<= 1) es += __shfl_xor(es, m, 64);
    if (tid == 0) atomicAdd(Lacc + b, es);
  }
  __syncthreads();

  // ---- weighted context: c[d] = sum_r e_r * values[r][d], from bf16 LDS ----
  int d0 = tid * 2;
  float c0 = 0.f, c1 = 0.f;
  for (int r = 0; r < RR; ++r) {
    float w = wlds[r];
    unsigned int pk = *(const unsigned int*)(&Alds[r * ASTR + d0]);
    c0 += w * bf2f(pk & 0xFFFFu);
    c1 += w * bf2f(pk >> 16);
  }
  atomicAdd(Cacc + b * ND + d0, c0);
  atomicAdd(Cacc + b * ND + d0 + 1, c1);
}

// ---------------- finalize: divide by denom ----------------
__global__ void finalize(const float* __restrict__ Cacc, const float* __restrict__ Lacc,
                         float* __restrict__ out) {
  int idx = blockIdx.x * 256 + threadIdx.x;   // 147456 total
  if (idx < NB * ND) {
    int b = idx >> 9;
    out[idx] = Cacc[idx] / Lacc[b];
  } else {
    int j = idx - NB * ND;
    int b = j >> 12;
    out[idx] = out[idx] / Lacc[b];
  }
}

extern "C" void kernel_launch(void* const* d_in, const int* in_sizes, int n_in,
                              void* d_out, int out_size, void* d_ws, size_t ws_size,
                              hipStream_t stream) {
  const float* query  = (const float*)d_in[0];
  const float* values = (const float*)d_in[1];
  const float* W1     = (const float*)d_in[2];
  const float* b1     = (const float*)d_in[3];
  const float* W2     = (const float*)d_in[4];
  const float* b2     = (const float*)d_in[5];
  const float* V      = (const float*)d_in[6];
  const float* bv     = (const float*)d_in[7];
  float* out = (float*)d_out;

  char* ws = (char*)d_ws;
  float* Cacc = (float*)ws;                          // 32*512*4 = 65536 B
  float* Lacc = (float*)(ws + 65536);                // 128 B
  float* qb   = (float*)(ws + 66048);                // 16384 B
  unsigned short* w2t = (unsigned short*)(ws + 66048 + 16384);  // 131072 B

  hipMemsetAsync(ws, 0, 66048, stream);              // zero Cacc + Lacc

  prep_qb <<<16, 256, 0, stream>>>(query, W1, b1, b2, qb);
  prep_w2t<<<256, 256, 0, stream>>>(W2, w2t);
  fused_attn<<<NB * (NS / RR), 256, 0, stream>>>(values, qb, w2t, V, bv,
                                                 out + NB * ND, Cacc, Lacc);
  finalize<<<(NB * ND + NB * NS) / 256, 256, 0, stream>>>(Cacc, Lacc, out);
}